// Round 1
// baseline (2081.169 us; speedup 1.0000x reference)
//
#include <hip/hip_runtime.h>

#define NN 50000
#define NE 800000
#define NG 256
#define BN_EPS 1e-5f

__device__ __forceinline__ float sigm(float x) { return 1.0f / (1.0f + __expf(-x)); }
__device__ __forceinline__ float sofp(float x) { return fmaxf(x, 0.0f) + __logf(1.0f + __expf(-fabsf(x))); }

// ---------------- node linear ----------------
// blockIdx.y = m: 0: Tdst[:,0:128]   = x@Wf[0:128]   + bf
//                 1: Tsrc[:,0:128]   = x@Wf[128:256]
//                 2: Tdst[:,128:256] = x@Ws[0:128]   + bs
//                 3: Tsrc[:,128:256] = x@Ws[128:256]
__global__ __launch_bounds__(256) void k_node_linear(
    const float* __restrict__ x,
    const float* __restrict__ Wf, const float* __restrict__ Ws,
    const float* __restrict__ bf, const float* __restrict__ bs,
    float* __restrict__ Tdst, float* __restrict__ Tsrc)
{
    const int m = blockIdx.y;
    const int n0 = blockIdx.x * 64;
    const int tid = threadIdx.x;
    const int tx = tid & 15;   // channel group (8 ch each)
    const int ty = tid >> 4;   // node group (4 nodes each)
    const float* W = ((m & 2) ? Ws : Wf) + (size_t)(m & 1) * 128 * 128;

    __shared__ float As[16][64];
    __shared__ float Bs[16][128];

    float acc[4][8];
#pragma unroll
    for (int i = 0; i < 4; ++i)
#pragma unroll
        for (int j = 0; j < 8; ++j) acc[i][j] = 0.0f;

    const int lr = tid >> 2;        // 0..63 node row for A load
    const int lq = tid & 3;         // float4 group within 16 k's
    const int br = tid >> 5;        // 0..7 k-row for B load
    const int bc = (tid & 31) * 4;  // col for B load

    for (int kc = 0; kc < 128; kc += 16) {
        float4 av = make_float4(0.f, 0.f, 0.f, 0.f);
        if (n0 + lr < NN) av = *(const float4*)(x + (size_t)(n0 + lr) * 128 + kc + lq * 4);
        const float4 b0 = *(const float4*)(W + (size_t)(kc + br) * 128 + bc);
        const float4 b1 = *(const float4*)(W + (size_t)(kc + br + 8) * 128 + bc);
        __syncthreads();
        As[lq * 4 + 0][lr] = av.x;
        As[lq * 4 + 1][lr] = av.y;
        As[lq * 4 + 2][lr] = av.z;
        As[lq * 4 + 3][lr] = av.w;
        *(float4*)&Bs[br][bc] = b0;
        *(float4*)&Bs[br + 8][bc] = b1;
        __syncthreads();
#pragma unroll
        for (int k = 0; k < 16; ++k) {
            float a[4], b[8];
#pragma unroll
            for (int i = 0; i < 4; ++i) a[i] = As[k][ty * 4 + i];
            const float4 q0 = *(const float4*)&Bs[k][tx * 8];
            const float4 q1 = *(const float4*)&Bs[k][tx * 8 + 4];
            b[0] = q0.x; b[1] = q0.y; b[2] = q0.z; b[3] = q0.w;
            b[4] = q1.x; b[5] = q1.y; b[6] = q1.z; b[7] = q1.w;
#pragma unroll
            for (int i = 0; i < 4; ++i)
#pragma unroll
                for (int j = 0; j < 8; ++j) acc[i][j] = fmaf(a[i], b[j], acc[i][j]);
        }
    }

    const float* bias = (m == 0) ? bf : ((m == 2) ? bs : nullptr);
    float bv[8];
#pragma unroll
    for (int j = 0; j < 8; ++j) bv[j] = bias ? bias[tx * 8 + j] : 0.0f;
    float* outb = ((m & 1) ? Tsrc : Tdst) + ((m & 2) ? 128 : 0);
#pragma unroll
    for (int i = 0; i < 4; ++i) {
        const int n = n0 + ty * 4 + i;
        if (n < NN) {
            float4 r0, r1;
            r0.x = acc[i][0] + bv[0]; r0.y = acc[i][1] + bv[1];
            r0.z = acc[i][2] + bv[2]; r0.w = acc[i][3] + bv[3];
            r1.x = acc[i][4] + bv[4]; r1.y = acc[i][5] + bv[5];
            r1.z = acc[i][6] + bv[6]; r1.w = acc[i][7] + bv[7];
            *(float4*)(outb + (size_t)n * 256 + tx * 8) = r0;
            *(float4*)(outb + (size_t)n * 256 + tx * 8 + 4) = r1;
        }
    }
}

// ---------------- fused edge kernel ----------------
// per edge: lin = T*[gather] + ea @ W[256:320]; msg = sigm(f)*sofp(s); atomicAdd to xout[dst]
__global__ __launch_bounds__(256) void k_edge(
    const float* __restrict__ Tdst, const float* __restrict__ Tsrc,
    const float* __restrict__ Wf, const float* __restrict__ Ws,
    const int* __restrict__ ei, const float* __restrict__ ea,
    float* __restrict__ xout)
{
    __shared__ float Wl[64][256];  // [k][0:128]=Wf edge rows, [k][128:256]=Ws edge rows
    const int tid = threadIdx.x;
    for (int i = tid; i < 64 * 128; i += 256) {
        const int k = i >> 7, c = i & 127;
        Wl[k][c]       = Wf[(size_t)(256 + k) * 128 + c];
        Wl[k][128 + c] = Ws[(size_t)(256 + k) * 128 + c];
    }
    __syncthreads();

    const int lane = tid & 63;
    const int c0 = lane * 2;                    // this lane's 2 channels
    const int gw = blockIdx.x * 4 + (tid >> 6); // global wave id
    const int nw = gridDim.x * 4;

    for (int chk = gw; chk < NE / 8; chk += nw) {
        const int e0 = chk * 8;
        float acf[8][2], acs[8][2];
#pragma unroll
        for (int i = 0; i < 8; ++i) { acf[i][0] = acf[i][1] = acs[i][0] = acs[i][1] = 0.0f; }

        float ev[8][4], evn[8][4];
#pragma unroll
        for (int i = 0; i < 8; ++i) {
            const float4 t = *(const float4*)(ea + (size_t)(e0 + i) * 64);
            ev[i][0] = t.x; ev[i][1] = t.y; ev[i][2] = t.z; ev[i][3] = t.w;
        }
        for (int kb = 0; kb < 16; ++kb) {
            if (kb < 15) {
#pragma unroll
                for (int i = 0; i < 8; ++i) {
                    const float4 t = *(const float4*)(ea + (size_t)(e0 + i) * 64 + (kb + 1) * 4);
                    evn[i][0] = t.x; evn[i][1] = t.y; evn[i][2] = t.z; evn[i][3] = t.w;
                }
            }
#pragma unroll
            for (int kk = 0; kk < 4; ++kk) {
                const int k = kb * 4 + kk;
                const float2 wfv = *(const float2*)&Wl[k][c0];
                const float2 wsv = *(const float2*)&Wl[k][128 + c0];
#pragma unroll
                for (int i = 0; i < 8; ++i) {
                    const float ek = ev[i][kk];
                    acf[i][0] = fmaf(ek, wfv.x, acf[i][0]);
                    acf[i][1] = fmaf(ek, wfv.y, acf[i][1]);
                    acs[i][0] = fmaf(ek, wsv.x, acs[i][0]);
                    acs[i][1] = fmaf(ek, wsv.y, acs[i][1]);
                }
            }
            if (kb < 15) {
#pragma unroll
                for (int i = 0; i < 8; ++i) {
                    ev[i][0] = evn[i][0]; ev[i][1] = evn[i][1];
                    ev[i][2] = evn[i][2]; ev[i][3] = evn[i][3];
                }
            }
        }
        // epilogue: gather node tables, nonlinearity, scatter-add
#pragma unroll
        for (int i = 0; i < 8; ++i) {
            const int e = e0 + i;
            const int sn = ei[e];        // src
            const int dn = ei[NE + e];   // dst
            const float2 tdf = *(const float2*)(Tdst + (size_t)dn * 256 + c0);
            const float2 tds = *(const float2*)(Tdst + (size_t)dn * 256 + 128 + c0);
            const float2 tsf = *(const float2*)(Tsrc + (size_t)sn * 256 + c0);
            const float2 tss = *(const float2*)(Tsrc + (size_t)sn * 256 + 128 + c0);
            const float F0 = acf[i][0] + tdf.x + tsf.x;
            const float F1 = acf[i][1] + tdf.y + tsf.y;
            const float S0 = acs[i][0] + tds.x + tss.x;
            const float S1 = acs[i][1] + tds.y + tss.y;
            atomicAdd(xout + (size_t)dn * 128 + c0,     sigm(F0) * sofp(S0));
            atomicAdd(xout + (size_t)dn * 128 + c0 + 1, sigm(F1) * sofp(S1));
        }
    }
}

// ---------------- batchnorm ----------------
__global__ __launch_bounds__(256) void k_bn_stats(const float* __restrict__ xv, float* __restrict__ stats)
{
    const int c = threadIdx.x & 127;
    const int half = threadIdx.x >> 7;
    float s = 0.0f, q = 0.0f;
    for (int r = blockIdx.x * 2 + half; r < NN; r += gridDim.x * 2) {
        const float v = xv[(size_t)r * 128 + c];
        s += v; q = fmaf(v, v, q);
    }
    __shared__ float sh[2][128];
    if (half) { sh[0][c] = s; sh[1][c] = q; }
    __syncthreads();
    if (!half) {
        s += sh[0][c]; q += sh[1][c];
        atomicAdd(&stats[c], s);
        atomicAdd(&stats[128 + c], q);
    }
}

__global__ void k_bn_finalize(const float* __restrict__ stats, const float* __restrict__ g,
                              const float* __restrict__ be, float* __restrict__ ab)
{
    const int c = threadIdx.x;
    const float mu = stats[c] * (1.0f / NN);
    const float var = stats[128 + c] * (1.0f / NN) - mu * mu;
    const float a = g[c] * rsqrtf(var + BN_EPS);
    ab[c] = a;
    ab[128 + c] = fmaf(-mu, a, be[c]);
}

__global__ __launch_bounds__(256) void k_bn_apply(float* __restrict__ xv, const float* __restrict__ ab)
{
    const size_t i = (size_t)blockIdx.x * 256 + threadIdx.x; // one float4 each; grid exactly covers
    const int c = ((int)i & 31) * 4;
    float4 v = ((float4*)xv)[i];
    v.x = fmaf(v.x, ab[c],     ab[128 + c]);
    v.y = fmaf(v.y, ab[c + 1], ab[128 + c + 1]);
    v.z = fmaf(v.z, ab[c + 2], ab[128 + c + 2]);
    v.w = fmaf(v.w, ab[c + 3], ab[128 + c + 3]);
    ((float4*)xv)[i] = v;
}

// ---------------- global mean pool ----------------
__global__ __launch_bounds__(256) void k_pool(const float* __restrict__ xv, const int* __restrict__ bat,
                                              float* __restrict__ pool, float* __restrict__ cnt)
{
    const int c = threadIdx.x & 127;
    const int half = threadIdx.x >> 7;
    for (int r = blockIdx.x * 2 + half; r < NN; r += gridDim.x * 2) {
        const int g = bat[r];
        atomicAdd(&pool[(size_t)g * 128 + c], xv[(size_t)r * 128 + c]);
        if (c == 0) atomicAdd(&cnt[g], 1.0f);
    }
}

__global__ __launch_bounds__(256) void k_pool_fin(const float* __restrict__ pool, const float* __restrict__ cnt,
                                                  float* __restrict__ out)
{
    const int i = blockIdx.x * 256 + threadIdx.x;
    out[i] = pool[i] / fmaxf(cnt[i >> 7], 1.0f);
}

extern "C" void kernel_launch(void* const* d_in, const int* in_sizes, int n_in,
                              void* d_out, int out_size, void* d_ws, size_t ws_size,
                              hipStream_t stream)
{
    const float* x   = (const float*)d_in[0];
    const int*   ei  = (const int*)d_in[1];
    const float* ea  = (const float*)d_in[2];
    const int*   bat = (const int*)d_in[3];
    const float* Wf[2] = { (const float*)d_in[4],  (const float*)d_in[10] };
    const float* bf[2] = { (const float*)d_in[5],  (const float*)d_in[11] };
    const float* Ws[2] = { (const float*)d_in[6],  (const float*)d_in[12] };
    const float* bs[2] = { (const float*)d_in[7],  (const float*)d_in[13] };
    const float* gm[2] = { (const float*)d_in[8],  (const float*)d_in[14] };
    const float* be[2] = { (const float*)d_in[9],  (const float*)d_in[15] };

    float* wsp = (float*)d_ws;
    float* Tdst = wsp;                               // [N][256]
    float* Tsrc = Tdst + (size_t)NN * 256;           // [N][256]
    float* xb0  = Tsrc + (size_t)NN * 256;           // [N][128]
    float* xb1  = xb0 + (size_t)NN * 128;            // [N][128]
    float* stats = xb1 + (size_t)NN * 128;           // 256
    float* ab    = stats + 256;                      // 256
    float* pool  = ab + 256;                         // [G][128]
    float* cnt   = pool + (size_t)NG * 128;          // G
    float* xb[2] = { xb0, xb1 };

    hipMemsetAsync(pool, 0, ((size_t)NG * 128 + NG) * sizeof(float), stream);

    const float* xin = x;
    for (int l = 0; l < 2; ++l) {
        k_node_linear<<<dim3(782, 4), 256, 0, stream>>>(xin, Wf[l], Ws[l], bf[l], bs[l], Tdst, Tsrc);
        hipMemcpyAsync(xb[l], xin, (size_t)NN * 128 * sizeof(float), hipMemcpyDeviceToDevice, stream);
        k_edge<<<1000, 256, 0, stream>>>(Tdst, Tsrc, Wf[l], Ws[l], ei, ea, xb[l]);
        hipMemsetAsync(stats, 0, 256 * sizeof(float), stream);
        k_bn_stats<<<256, 256, 0, stream>>>(xb[l], stats);
        k_bn_finalize<<<1, 128, 0, stream>>>(stats, gm[l], be[l], ab);
        k_bn_apply<<<6250, 256, 0, stream>>>(xb[l], ab);
        xin = xb[l];
    }
    k_pool<<<256, 256, 0, stream>>>(xb[1], bat, pool, cnt);
    k_pool_fin<<<NG * 128 / 256, 256, 0, stream>>>(pool, cnt, (float*)d_out);
}